// Round 2
// baseline (328.336 us; speedup 1.0000x reference)
//
#include <hip/hip_runtime.h>
#include <math.h>

typedef unsigned short ushort_t;
typedef __attribute__((ext_vector_type(8))) short short8;
typedef __attribute__((ext_vector_type(4))) float f32x4;

// Problem constants (fixed by setup_inputs)
#define NN    20000
#define DEG   16
constexpr int MAXL2 = 1 + DEG;            // 17
constexpr int MAXL1 = MAXL2 + MAXL2*DEG;  // 289
constexpr int L0PAD = 73 * 64;            // 4672 (guard-free MFMA tiles); c1*16 <= 4624 fits

__device__ __forceinline__ ushort_t f2bf(float f) {
    unsigned u = __float_as_uint(f);
    return (ushort_t)((u + 0x7FFFu + ((u >> 16) & 1u)) >> 16);   // RTN-even
}

// ---------------- fused 32x32 transpose + f32->bf16 : W[K][N] -> WT[N][K] ----------------
__device__ void transpose_tile(const float* __restrict__ W, ushort_t* __restrict__ WT,
                               int b, int nshift, int K) {
    __shared__ float tile[32][33];
    int t = threadIdx.x;
    int N = 32 << nshift;
    int bx = b & ((1 << nshift) - 1), by = b >> nshift;
    int i0 = t >> 3, j0 = (t & 7) * 4;
    int k = by * 32 + i0, n0 = bx * 32;
    float4 v = *(const float4*)(W + (size_t)k * N + n0 + j0);
    tile[i0][j0] = v.x; tile[i0][j0 + 1] = v.y; tile[i0][j0 + 2] = v.z; tile[i0][j0 + 3] = v.w;
    __syncthreads();
    int n = n0 + i0, kc = j0;
    ushort_t* p = WT + (size_t)n * K + by * 32 + kc;
    p[0] = f2bf(tile[kc][i0]);     p[1] = f2bf(tile[kc + 1][i0]);
    p[2] = f2bf(tile[kc + 2][i0]); p[3] = f2bf(tile[kc + 3][i0]);
}

// ---------------- frontier (block 0: BFS levels 2+1 only) + ws zero + both W transposes --------
// Level-0 dedup REMOVED: list0 positions are the static mapping r -> senders[list1[r>>4]*16+(r&15)]
__global__ __launch_bounds__(256)
void k_frontier(const int* __restrict__ senders,
                int* __restrict__ list2, int* __restrict__ inv2,
                int* __restrict__ list1, int* __restrict__ inv1,
                int* __restrict__ cnts,
                const float* __restrict__ aw0, ushort_t* __restrict__ awT,
                const float* __restrict__ aw1, ushort_t* __restrict__ awT1,
                float4* __restrict__ zp, int n4, int nzb) {
    int t = threadIdx.x;
    int bb = (int)blockIdx.x;
    if (bb > 0) {
        int b = bb - 1;
        if (b < nzb) {                       // zero the atomic-accumulator region
            int i = b * 256 + t;
            if (i < n4) zp[i] = make_float4(0.f, 0.f, 0.f, 0.f);
            return;
        }
        b -= nzb;
        if (b < 512) { transpose_tile(aw0, awT, b, 4, 1024); return; }   // aw0 [1024][512]
        b -= 512;
        transpose_tile(aw1, awT1, b, 3, 512);                            // aw1 [512][256]
        return;
    }
    __shared__ unsigned bm[625];
    __shared__ int cnt;
    __shared__ int lloc[MAXL2];
    auto clear = [&]() { for (int i = t; i < 625; i += 256) bm[i] = 0u; if (t == 0) cnt = 0; };
    clear(); __syncthreads();
    if (t < 17) {
        int node = (t < 16) ? senders[14 * DEG + t] : 14;
        unsigned bit = 1u << (node & 31);
        unsigned old = atomicOr(&bm[node >> 5], bit);
        if (!(old & bit)) { int p = atomicAdd(&cnt, 1); list2[p] = node; inv2[node] = p; lloc[p] = node; }
    }
    __syncthreads();
    int c2 = cnt;
    if (t == 0) cnts[2] = c2;
    __syncthreads(); clear(); __syncthreads();
    for (int i = t; i < c2 * 17; i += 256) {
        int r = i / 17, k = i - r * 17;
        int node = (k < 16) ? senders[lloc[r] * DEG + k] : lloc[r];
        unsigned bit = 1u << (node & 31);
        unsigned old = atomicOr(&bm[node >> 5], bit);
        if (!(old & bit)) { int p = atomicAdd(&cnt, 1); list1[p] = node; inv1[node] = p; }
    }
    __syncthreads();
    if (t == 0) { int c1 = cnt; cnts[1] = c1; cnts[0] = c1 * 16; }
}

// ---------------- gather X rows -> bf16, deriving inv0 inline (no dedup; races benign) ---------
__global__ __launch_bounds__(256)
void k_prep(const float* __restrict__ X, const int* __restrict__ senders,
            const int* __restrict__ list1, const int* __restrict__ cnts,
            int* __restrict__ inv0, ushort_t* __restrict__ Xg) {
    int r = blockIdx.x;
    int t = threadIdx.x;
    int rc = cnts[0];
    ushort_t o0 = 0, o1 = 0, o2 = 0, o3 = 0;
    if (r < rc) {
        int n = list1[r >> 4];                 // broadcast load (all lanes same addr)
        int s = senders[n * DEG + (r & 15)];
        if (t == 0) inv0[s] = r;               // duplicate writers: any winner valid (rows identical)
        float4 v = *(const float4*)(X + (size_t)s * 1024 + t * 4);
        o0 = f2bf(v.x); o1 = f2bf(v.y); o2 = f2bf(v.z); o3 = f2bf(v.w);
    }
    ushort_t* p = Xg + (size_t)r * 1024 + t * 4;
    p[0] = o0; p[1] = o1; p[2] = o2; p[3] = o3;    // pad rows -> zeros (guard-free MFMA)
}

// ---------------- bf16 MFMA logits GEMM: lgc[r] += sum_c relu(Xg[r]@W)[c]*aq[c] ----------------
// Used for layer 0 (K=1024, NC=512) AND layer 1 (K=512, NC=256, h1 in bf16).
// NOTE: fused relu epilogue => split-K is FORBIDDEN (relu of partial sums is wrong).
__global__ __launch_bounds__(256)
void k_logits_mfma(const ushort_t* __restrict__ Xg,  // [rows_pad][K]
                   const ushort_t* __restrict__ WT,  // [NC][K]
                   const float* __restrict__ aq, float* __restrict__ lgc,
                   const int* __restrict__ cnt, int K) {
    __shared__ short As[64 * 40];
    __shared__ short Bs[64 * 40];
    int rcnt = *cnt;
    int row0 = blockIdx.x * 64;
    if (row0 >= rcnt) return;
    int col0 = blockIdx.y * 64;
    int t = threadIdx.x;
    int w = t >> 6, lane = t & 63;

    int sr = t >> 2, sk = (t & 3) * 8;
    const ushort_t* ap = Xg + (size_t)(row0 + sr) * K + sk;
    const ushort_t* bp = WT + (size_t)(col0 + sr) * K + sk;

    int fm = lane & 15, fq = lane >> 4;
    const short* arow = As + (w * 16 + fm) * 40 + fq * 8;
    const short* brow = Bs + fm * 40 + fq * 8;

    f32x4 acc0 = {0.f,0.f,0.f,0.f}, acc1 = {0.f,0.f,0.f,0.f};
    f32x4 acc2 = {0.f,0.f,0.f,0.f}, acc3 = {0.f,0.f,0.f,0.f};

    short8 pa = *(const short8*)(ap);
    short8 pb = *(const short8*)(bp);
    for (int k0 = 0; k0 < K; k0 += 32) {
        *(short8*)(As + sr * 40 + sk) = pa;
        *(short8*)(Bs + sr * 40 + sk) = pb;
        __syncthreads();
        if (k0 + 32 < K) {
            pa = *(const short8*)(ap + k0 + 32);
            pb = *(const short8*)(bp + k0 + 32);
        }
        short8 af = *(const short8*)arow;
        short8 b0 = *(const short8*)(brow);
        short8 b1 = *(const short8*)(brow + 16 * 40);
        short8 b2 = *(const short8*)(brow + 32 * 40);
        short8 b3 = *(const short8*)(brow + 48 * 40);
        acc0 = __builtin_amdgcn_mfma_f32_16x16x32_bf16(af, b0, acc0, 0, 0, 0);
        acc1 = __builtin_amdgcn_mfma_f32_16x16x32_bf16(af, b1, acc1, 0, 0, 0);
        acc2 = __builtin_amdgcn_mfma_f32_16x16x32_bf16(af, b2, acc2, 0, 0, 0);
        acc3 = __builtin_amdgcn_mfma_f32_16x16x32_bf16(af, b3, acc3, 0, 0, 0);
        __syncthreads();
    }

    float aqv0 = aq[col0 + fm], aqv1 = aq[col0 + 16 + fm];
    float aqv2 = aq[col0 + 32 + fm], aqv3 = aq[col0 + 48 + fm];
#pragma unroll
    for (int r = 0; r < 4; r++) {
        float v = fmaxf(acc0[r], 0.f) * aqv0 + fmaxf(acc1[r], 0.f) * aqv1
                + fmaxf(acc2[r], 0.f) * aqv2 + fmaxf(acc3[r], 0.f) * aqv3;
#pragma unroll
        for (int off = 1; off < 16; off <<= 1) v += __shfl_xor(v, off);
        if (fm == 0) atomicAdd(&lgc[row0 + w * 16 + fq * 4 + r], v);
    }
}

// ---------------- generic pipelined fp32 GEMM (64x64, BK=32) -- used for mm0 only --------------
__global__ __launch_bounds__(256)
void k_matmul(const float* __restrict__ A1, const float* __restrict__ A2,
              const int* __restrict__ list, const int* __restrict__ inv,
              const float* __restrict__ B, const float* __restrict__ aq,
              float* __restrict__ C, const int* __restrict__ cnt,
              int amode, int omode, int K1, int K2, int NC, int KS) {
    __shared__ float As[32][68];
    __shared__ float Bs[32][64];
    __shared__ float rowsum[64];

    int rcnt = *cnt;
    int row0 = blockIdx.x * 64;
    if (row0 >= rcnt) return;
    int col0 = blockIdx.y * 64;
    int K = K1 + K2;
    int kbeg = blockIdx.z * KS;
    int kend = kbeg + KS; if (kend > K) kend = K;

    int t = threadIdx.x;
    int ty = t >> 4, tx = t & 15;
    int lr = t >> 2, kaoff = (t & 3) * 4;
    int grow = row0 + lr;
    bool rowValid = grow < rcnt;
    const float* rp1 = A1;
    const float* rp2 = A2;
    if (rowValid) {
        int hrow;
        if (amode == 0) hrow = grow;
        else { int node = list[grow]; hrow = (amode == 2) ? inv[node] : node; }
        rp1 = A1 + (size_t)hrow * K1;
        rp2 = A2 + (size_t)grow * K2;
    }
    const float* Bp = B + col0;
    int bidx0 = t, bidx1 = t + 256;

    auto loadA = [&](int k) -> float4 {
        if (!rowValid) return make_float4(0.f, 0.f, 0.f, 0.f);
        const float* src = (k < K1) ? (rp1 + k) : (rp2 + (k - K1));
        return *(const float4*)src;
    };
    auto loadB = [&](int idx, int k0) -> float4 {
        int row = idx >> 4, c4 = (idx & 15) * 4;
        return *(const float4*)(Bp + (size_t)(k0 + row) * NC + c4);
    };

    float4 pa0 = loadA(kbeg + kaoff);
    float4 pa1 = loadA(kbeg + kaoff + 16);
    float4 pb0 = loadB(bidx0, kbeg);
    float4 pb1 = loadB(bidx1, kbeg);

    float acc[4][4] = {};
    for (int k0 = kbeg; k0 < kend; k0 += 32) {
        As[kaoff + 0][lr] = pa0.x; As[kaoff + 1][lr] = pa0.y;
        As[kaoff + 2][lr] = pa0.z; As[kaoff + 3][lr] = pa0.w;
        As[kaoff + 16][lr] = pa1.x; As[kaoff + 17][lr] = pa1.y;
        As[kaoff + 18][lr] = pa1.z; As[kaoff + 19][lr] = pa1.w;
        *(float4*)&Bs[bidx0 >> 4][(bidx0 & 15) * 4] = pb0;
        *(float4*)&Bs[bidx1 >> 4][(bidx1 & 15) * 4] = pb1;
        __syncthreads();
        if (k0 + 32 < kend) {
            pa0 = loadA(k0 + 32 + kaoff);
            pa1 = loadA(k0 + 32 + kaoff + 16);
            pb0 = loadB(bidx0, k0 + 32);
            pb1 = loadB(bidx1, k0 + 32);
        }
#pragma unroll
        for (int kk = 0; kk < 32; kk++) {
            float4 a4 = *(const float4*)&As[kk][ty * 4];
            float4 b4 = *(const float4*)&Bs[kk][tx * 4];
            float a[4] = {a4.x, a4.y, a4.z, a4.w};
            float b[4] = {b4.x, b4.y, b4.z, b4.w};
#pragma unroll
            for (int i = 0; i < 4; i++)
#pragma unroll
                for (int j = 0; j < 4; j++) acc[i][j] += a[i] * b[j];
        }
        __syncthreads();
    }

    if (omode == 0) {
#pragma unroll
        for (int i = 0; i < 4; i++) {
            int r = row0 + ty * 4 + i;
            if (r < rcnt) {
                float* Crow = C + (size_t)r * NC + col0 + tx * 4;
#pragma unroll
                for (int j = 0; j < 4; j++) atomicAdd(&Crow[j], acc[i][j]);
            }
        }
    } else {
        if (t < 64) rowsum[t] = 0.f;
        __syncthreads();
        float aqv[4];
#pragma unroll
        for (int j = 0; j < 4; j++) aqv[j] = aq[col0 + tx * 4 + j];
#pragma unroll
        for (int i = 0; i < 4; i++) {
            float s = 0.f;
#pragma unroll
            for (int j = 0; j < 4; j++) {
                float v = acc[i][j];
                v = v > 0.f ? v : 0.f;
                s += v * aqv[j];
            }
            atomicAdd(&rowsum[ty * 4 + i], s);
        }
        __syncthreads();
        if (t < 64) {
            int r = row0 + t;
            if (r < rcnt) atomicAdd(&C[r], rowsum[t]);
        }
    }
}

// ---------------- bias + relu epilogue, dual f32 + bf16 output ----------------
__global__ void k_bias_relu(const float* __restrict__ C, const float* __restrict__ b,
                            float* __restrict__ H, ushort_t* __restrict__ Hb,
                            const int* __restrict__ cnt, int ncShift) {
    int rcnt = *cnt;
    int NC = 1 << ncShift;
    int e = blockIdx.x * 256 + threadIdx.x;
    int r = e >> ncShift;
    if (r >= rcnt) return;
    int c = e & (NC - 1);
    float v = C[(size_t)r * NC + c] + b[c];
    v = v > 0.f ? v : 0.f;
    H[(size_t)r * NC + c] = v;
    Hb[(size_t)r * NC + c] = f2bf(v);
}

// ---------------- attention aggregate (layer 0), float4-vectorized ----------------
__global__ __launch_bounds__(256)
void k_agg(const float* __restrict__ Hsrc, const int* __restrict__ invH,
           const float* __restrict__ lgc, const int* __restrict__ invL,
           const int* __restrict__ senders,
           const int* __restrict__ listN, const int* __restrict__ cntN,
           float* __restrict__ hN, int din) {
    __shared__ int   s_row[DEG];
    __shared__ float s_w[DEG];
    __shared__ float s_scale;
    int b = blockIdx.x;
    if (b >= *cntN) return;
    int n = listN[b];
    int t = threadIdx.x;
    if (t < DEG) {
        int s = senders[n * DEG + t];
        s_row[t] = invH ? invH[s] : s;
        s_w[t] = lgc[invL ? invL[s] : s];
    }
    __syncthreads();
    if (t == 0) {
        float m = -1e30f;
        for (int k = 0; k < DEG; k++) m = fmaxf(m, s_w[k]);
        float d = 0.f;
        for (int k = 0; k < DEG; k++) { float w = __expf(s_w[k] - m); s_w[k] = w; d += w; }
        s_scale = 1.f / d;
    }
    __syncthreads();
    float scale = s_scale;
    for (int dI = t * 4; dI < din; dI += 1024) {
        float4 acc = make_float4(0.f, 0.f, 0.f, 0.f);
#pragma unroll
        for (int k = 0; k < DEG; k++) {
            float w = s_w[k];
            float4 v = *(const float4*)(Hsrc + (size_t)s_row[k] * din + dI);
            acc.x += w * v.x; acc.y += w * v.y; acc.z += w * v.z; acc.w += w * v.w;
        }
        acc.x *= scale; acc.y *= scale; acc.z *= scale; acc.w *= scale;
        *(float4*)(hN + (size_t)b * din + dI) = acc;
    }
}

// ---------------- fused layer-1 tail: softmax(lgc1) agg + [h1|hN1]@lw1 + bias + relu -> h2 -----
// 8 blocks x 32 output cols; each block redundantly computes hN1 (17x512) in LDS, then GEMM.
__global__ __launch_bounds__(256)
void k_tail1(const float* __restrict__ h1, const float* __restrict__ lgc1,
             const int* __restrict__ senders, const int* __restrict__ list2,
             const int* __restrict__ inv1, const int* __restrict__ cnts,
             const float* __restrict__ lw1, const float* __restrict__ lb1,
             float* __restrict__ h2) {
    __shared__ float As[17][1024];      // [j][0:512)=own h1 row, [512:1024)=hN1 row
    __shared__ float sw[17][16];
    __shared__ int   srow[17][16];
    __shared__ int   orow[17];
    __shared__ float psum[8][17 * 32];
    int c2 = cnts[2];
    int t = threadIdx.x;
    int b = blockIdx.x;

    // BUGFIX (round 1): c2*16 can be 272 > 256 threads -> strided loop, not a single guard.
    for (int i = t; i < c2 * 16; i += 256) {
        int j = i >> 4, k = i & 15;
        int s = senders[list2[j] * DEG + k];
        int rr = inv1[s];
        srow[j][k] = rr;
        sw[j][k] = lgc1[rr];
    }
    if (t < c2) orow[t] = inv1[list2[t]];
    __syncthreads();
    if (t < c2) {
        float m = -1e30f;
        for (int k = 0; k < 16; k++) m = fmaxf(m, sw[t][k]);
        float d = 0.f;
        for (int k = 0; k < 16; k++) { float w = __expf(sw[t][k] - m); sw[t][k] = w; d += w; }
        float inv = 1.f / d;
        for (int k = 0; k < 16; k++) sw[t][k] *= inv;
    }
    __syncthreads();
    for (int e = t; e < c2 * 512; e += 256) {
        int j = e >> 9, d = e & 511;
        As[j][d] = h1[(size_t)orow[j] * 512 + d];
        float a = 0.f;
#pragma unroll
        for (int k = 0; k < 16; k++) a += sw[j][k] * h1[(size_t)srow[j][k] * 512 + d];
        As[j][512 + d] = a;
    }
    __syncthreads();
    // GEMM: thread = (col c in 0..31, k-slice s in 0..7 of 128)
    int c = t & 31, s = t >> 5;
    int gc = b * 32 + c;
    float acc[17];
#pragma unroll
    for (int j = 0; j < 17; j++) acc[j] = 0.f;
    for (int k = s * 128; k < s * 128 + 128; k += 4) {
        float b0 = lw1[(size_t)(k + 0) * 256 + gc];
        float b1 = lw1[(size_t)(k + 1) * 256 + gc];
        float b2 = lw1[(size_t)(k + 2) * 256 + gc];
        float b3 = lw1[(size_t)(k + 3) * 256 + gc];
#pragma unroll
        for (int j = 0; j < 17; j++) {
            float4 a = *(const float4*)&As[j][k];       // LDS broadcast across the 32 c-lanes
            acc[j] += a.x * b0 + a.y * b1 + a.z * b2 + a.w * b3;
        }
    }
#pragma unroll
    for (int j = 0; j < 17; j++) psum[s][j * 32 + c] = acc[j];
    __syncthreads();
    for (int e = t; e < c2 * 32; e += 256) {
        int j = e >> 5, cc = e & 31;
        float v = 0.f;
#pragma unroll
        for (int s2 = 0; s2 < 8; s2++) v += psum[s2][j * 32 + cc];
        v += lb1[b * 32 + cc];
        h2[(size_t)j * 256 + b * 32 + cc] = v > 0.f ? v : 0.f;
    }
}

// ---------------- fused layer-2 tail: logits2 + softmax + agg + [h2|hN2]@lw2 + out matvec ------
__global__ __launch_bounds__(512)
void k_tail2(const float* __restrict__ h2, const int* __restrict__ senders,
             const int* __restrict__ inv2, const int* __restrict__ cnts,
             const float* __restrict__ aw2, const float* __restrict__ aq2,
             const float* __restrict__ lw2, const float* __restrict__ lb2,
             const float* __restrict__ ow, const float* __restrict__ ob,
             float* __restrict__ out) {
    __shared__ float sh2[17][256];
    __shared__ float slog[17];
    __shared__ float swt[16];
    __shared__ int   srow2[16];
    __shared__ float hN2[256];
    __shared__ float sh3[128];
    __shared__ float part[4][128];
    __shared__ int   srow14;
    int c2 = cnts[2];
    int t = threadIdx.x;
    for (int e = t; e < c2 * 256; e += 512) sh2[e >> 8][e & 255] = h2[e];
    if (t < c2) slog[t] = 0.f;
    if (t < 16) srow2[t] = inv2[senders[14 * DEG + t]];
    if (t == 31) srow14 = inv2[14];
    __syncthreads();
    // logits2[j] = sum_c relu(h2[j] @ aw2[:,c]) * aq2[c]
    for (int p = t; p < c2 * 128; p += 512) {
        int j = p >> 7, c = p & 127;
        float dot = 0.f;
        for (int k = 0; k < 256; k += 4) {
            float4 a = *(const float4*)&sh2[j][k];
            dot += a.x * aw2[(k + 0) * 128 + c] + a.y * aw2[(k + 1) * 128 + c]
                 + a.z * aw2[(k + 2) * 128 + c] + a.w * aw2[(k + 3) * 128 + c];
        }
        float v = dot > 0.f ? dot : 0.f;
        atomicAdd(&slog[j], v * aq2[c]);
    }
    __syncthreads();
    if (t == 0) {
        float m = -1e30f;
        for (int k = 0; k < 16; k++) m = fmaxf(m, slog[srow2[k]]);
        float d = 0.f;
        for (int k = 0; k < 16; k++) { float w = __expf(slog[srow2[k]] - m); swt[k] = w; d += w; }
        float inv = 1.f / d;
        for (int k = 0; k < 16; k++) swt[k] *= inv;
    }
    __syncthreads();
    if (t < 256) {
        float a = 0.f;
#pragma unroll
        for (int k = 0; k < 16; k++) a += swt[k] * sh2[srow2[k]][t];
        hN2[t] = a;
    }
    __syncthreads();
    {
        int c = t & 127, s4 = t >> 7;
        float acc = 0.f;
        for (int k = s4 * 128; k < s4 * 128 + 128; k++) {
            float a = (k < 256) ? sh2[srow14][k] : hN2[k - 256];
            acc += a * lw2[(size_t)k * 128 + c];
        }
        part[s4][c] = acc;
    }
    __syncthreads();
    if (t < 128) {
        float v = part[0][t] + part[1][t] + part[2][t] + part[3][t] + lb2[t];
        sh3[t] = v > 0.f ? v : 0.f;
    }
    __syncthreads();
    {
        int o = t & 127, s4 = t >> 7;
        float acc = 0.f;
        for (int k = s4 * 32; k < s4 * 32 + 32; k++) acc += sh3[k] * ow[(size_t)k * 128 + o];
        part[s4][o] = acc;
    }
    __syncthreads();
    if (t < 128) out[t] = ob[t] + part[0][t] + part[1][t] + part[2][t] + part[3][t];
}

// ---------------- launch ----------------
extern "C" void kernel_launch(void* const* d_in, const int* in_sizes, int n_in,
                              void* d_out, int out_size, void* d_ws, size_t ws_size,
                              hipStream_t stream) {
    const float* X       = (const float*)d_in[0];
    const int*   senders = (const int*)d_in[1];
    const float* lw0 = (const float*)d_in[3];
    const float* lb0 = (const float*)d_in[4];
    const float* aw0 = (const float*)d_in[5];
    const float* aq0 = (const float*)d_in[6];
    const float* lw1 = (const float*)d_in[7];
    const float* lb1 = (const float*)d_in[8];
    const float* aw1 = (const float*)d_in[9];
    const float* aq1 = (const float*)d_in[10];
    const float* lw2 = (const float*)d_in[11];
    const float* lb2 = (const float*)d_in[12];
    const float* aw2 = (const float*)d_in[13];
    const float* aq2 = (const float*)d_in[14];
    const float* owp = (const float*)d_in[15];
    const float* obp = (const float*)d_in[16];
    float* out = (float*)d_out;

    char* ws = (char*)d_ws;
    size_t off = 0;
    auto alloc = [&](size_t nbytes) -> void* {
        void* p = ws + off;
        off += (nbytes + 255) & ~(size_t)255;
        return p;
    };
    // ---- zero-initialized region (contiguous from ws start; zeroed by k_frontier) ----
    float* lgc0     = (float*)alloc(L0PAD * 4);
    float* lgc1     = (float*)alloc(320 * 4);                 // padded to 5*64 rows
    float* C0       = (float*)alloc((size_t)MAXL1 * 512 * 4);
    ushort_t* h1b   = (ushort_t*)alloc((size_t)320 * 512 * 2); // bf16 h1, pad rows stay 0
    size_t zero_end = off;
    // ---- rest (poisoned; every read site guaranteed written first) ----
    int* inv0  = (int*)alloc(NN * 4);
    int* inv1  = (int*)alloc(NN * 4);
    int* inv2  = (int*)alloc(NN * 4);
    int* list1 = (int*)alloc(MAXL1 * 4);
    int* list2 = (int*)alloc(MAXL2 * 4);
    int* cnts  = (int*)alloc(4 * 4);
    ushort_t* Xg   = (ushort_t*)alloc((size_t)L0PAD * 1024 * 2);
    ushort_t* awT  = (ushort_t*)alloc((size_t)512 * 1024 * 2);   // aw0^T bf16 [512][1024]
    ushort_t* awT1 = (ushort_t*)alloc((size_t)256 * 512 * 2);    // aw1^T bf16 [256][512]
    float* hN0c = (float*)alloc((size_t)MAXL1 * 1024 * 4);
    float* h1c  = (float*)alloc((size_t)MAXL1 * 512 * 4);
    float* h2c  = (float*)alloc((size_t)MAXL2 * 256 * 4);
    (void)in_sizes; (void)n_in; (void)out_size; (void)ws_size;

    int nz4 = (int)(zero_end / 16);
    int nzb = (nz4 + 255) / 256;

    // 1. BFS levels 2+1 (block 0) || zero accumulators || transpose aw0+aw1 to bf16
    hipLaunchKernelGGL(k_frontier, dim3(1 + nzb + 512 + 128), dim3(256), 0, stream,
                       senders, list2, inv2, list1, inv1, cnts,
                       aw0, awT, aw1, awT1, (float4*)ws, nz4, nzb);
    // 2. gather X[list0] -> bf16 (list0/inv0 derived inline, no dedup)
    hipLaunchKernelGGL(k_prep, dim3(L0PAD), dim3(256), 0, stream,
                       X, senders, list1, cnts, inv0, Xg);
    // 3. layer-0 logits (bf16 MFMA, K=1024, NC=512)
    hipLaunchKernelGGL(k_logits_mfma, dim3(73, 8), dim3(256), 0, stream,
                       Xg, awT, aq0, lgc0, cnts + 0, 1024);
    // 4. layer-0 attention aggregate
    hipLaunchKernelGGL(k_agg, dim3(MAXL1), dim3(256), 0, stream,
                       X, (const int*)nullptr, lgc0, inv0, senders, list1, cnts + 1, hN0c, 1024);
    // 5. h1 = [X|hN0] @ lw0 (fp32, split-K 8)
    hipLaunchKernelGGL(k_matmul, dim3((MAXL1 + 63) / 64, 512 / 64, 8), dim3(256), 0, stream,
                       X, hN0c, list1, (int*)nullptr, lw0, aq0, C0, cnts + 1,
                       1, 0, 1024, 1024, 512, 256);
    // 6. bias+relu -> h1 (f32) + h1 (bf16)
    hipLaunchKernelGGL(k_bias_relu, dim3((MAXL1 * 512 + 255) / 256), dim3(256), 0, stream,
                       C0, lb0, h1c, h1b, cnts + 1, 9);
    // 7. layer-1 logits (bf16 MFMA, K=512, NC=256)
    hipLaunchKernelGGL(k_logits_mfma, dim3(5, 4), dim3(256), 0, stream,
                       h1b, awT1, aq1, lgc1, cnts + 1, 512);
    // 8. fused layer-1 tail -> h2 (17x256)
    hipLaunchKernelGGL(k_tail1, dim3(8), dim3(256), 0, stream,
                       h1c, lgc1, senders, list2, inv1, cnts, lw1, lb1, h2c);
    // 9. fused layer-2 tail -> out (128)
    hipLaunchKernelGGL(k_tail2, dim3(1), dim3(512), 0, stream,
                       h2c, senders, inv2, cnts, aw2, aq2, lw2, lb2, owp, obp, out);
}

// Round 3
// 265.688 us; speedup vs baseline: 1.2358x; 1.2358x over previous
//
#include <hip/hip_runtime.h>
#include <math.h>

typedef unsigned short ushort_t;
typedef __attribute__((ext_vector_type(8))) short short8;
typedef __attribute__((ext_vector_type(4))) float f32x4;

// Problem constants (fixed by setup_inputs)
#define NN    20000
#define DEG   16
constexpr int MAXL2 = 1 + DEG;            // 17
constexpr int MAXL1 = MAXL2 + MAXL2*DEG;  // 289
constexpr int L0PAD = 73 * 64;            // 4672 (guard-free MFMA tiles); c1*16 <= 4624 fits

__device__ __forceinline__ ushort_t f2bf(float f) {
    unsigned u = __float_as_uint(f);
    return (ushort_t)((u + 0x7FFFu + ((u >> 16) & 1u)) >> 16);   // RTN-even
}

// ---------------- fused 32x32 transpose + f32->bf16 : W[K][N] -> WT[N][K] ----------------
__device__ void transpose_tile(const float* __restrict__ W, ushort_t* __restrict__ WT,
                               int b, int nshift, int K) {
    __shared__ float tile[32][33];
    int t = threadIdx.x;
    int N = 32 << nshift;
    int bx = b & ((1 << nshift) - 1), by = b >> nshift;
    int i0 = t >> 3, j0 = (t & 7) * 4;
    int k = by * 32 + i0, n0 = bx * 32;
    float4 v = *(const float4*)(W + (size_t)k * N + n0 + j0);
    tile[i0][j0] = v.x; tile[i0][j0 + 1] = v.y; tile[i0][j0 + 2] = v.z; tile[i0][j0 + 3] = v.w;
    __syncthreads();
    int n = n0 + i0, kc = j0;
    ushort_t* p = WT + (size_t)n * K + by * 32 + kc;
    p[0] = f2bf(tile[kc][i0]);     p[1] = f2bf(tile[kc + 1][i0]);
    p[2] = f2bf(tile[kc + 2][i0]); p[3] = f2bf(tile[kc + 3][i0]);
}

// ---------------- frontier (block 0: BFS 2+1) + ws zero + W transposes + L3 warming ------------
__global__ __launch_bounds__(256)
void k_frontier(const int* __restrict__ senders,
                int* __restrict__ list2, int* __restrict__ inv2,
                int* __restrict__ list1, int* __restrict__ inv1,
                int* __restrict__ cnts,
                const float* __restrict__ aw0, ushort_t* __restrict__ awT,
                const float* __restrict__ aw1, ushort_t* __restrict__ awT1,
                const float* __restrict__ lw1, const float* __restrict__ aw2,
                const float* __restrict__ lw2, const float* __restrict__ ow,
                float* __restrict__ dummy,
                float4* __restrict__ zp, int n4, int nzb) {
    int t = threadIdx.x;
    int bb = (int)blockIdx.x;
    if (bb > 0) {
        int b = bb - 1;
        if (b < nzb) {                       // zero the atomic-accumulator region
            int i = b * 256 + t;
            if (i < n4) zp[i] = make_float4(0.f, 0.f, 0.f, 0.f);
            return;
        }
        b -= nzb;
        if (b < 512) { transpose_tile(aw0, awT, b, 4, 1024); return; }   // aw0 [1024][512]
        b -= 512;
        if (b < 128) { transpose_tile(aw1, awT1, b, 3, 512); return; }   // aw1 [512][256]
        b -= 128;
        // ---- L3 warming: stream tail weights so k_tail1/k_tail2 hit Infinity Cache ----
        // lw1: 64 blocks (1 MB), aw2: 8 (128 KB), lw2: 16 (256 KB), ow: 4 (64 KB); 16 KB/block
        const float4* src; int base;
        if (b < 64)       { src = (const float4*)lw1; base = b * 1024; }
        else if (b < 72)  { src = (const float4*)aw2; base = (b - 64) * 1024; }
        else if (b < 88)  { src = (const float4*)lw2; base = (b - 72) * 1024; }
        else              { src = (const float4*)ow;  base = (b - 88) * 1024; }
        float s = 0.f;
#pragma unroll
        for (int i = 0; i < 4; i++) {
            float4 v = src[base + i * 256 + t];
            s += v.x + v.y + v.z + v.w;
        }
        if (s == 1234.5678f) dummy[0] = s;   // keep loads live; practically never taken
        return;
    }
    __shared__ unsigned bm[625];
    __shared__ int cnt;
    __shared__ int lloc[MAXL2];
    auto clear = [&]() { for (int i = t; i < 625; i += 256) bm[i] = 0u; if (t == 0) cnt = 0; };
    clear(); __syncthreads();
    if (t < 17) {
        int node = (t < 16) ? senders[14 * DEG + t] : 14;
        unsigned bit = 1u << (node & 31);
        unsigned old = atomicOr(&bm[node >> 5], bit);
        if (!(old & bit)) { int p = atomicAdd(&cnt, 1); list2[p] = node; inv2[node] = p; lloc[p] = node; }
    }
    __syncthreads();
    int c2 = cnt;
    if (t == 0) cnts[2] = c2;
    __syncthreads(); clear(); __syncthreads();
    for (int i = t; i < c2 * 17; i += 256) {
        int r = i / 17, k = i - r * 17;
        int node = (k < 16) ? senders[lloc[r] * DEG + k] : lloc[r];
        unsigned bit = 1u << (node & 31);
        unsigned old = atomicOr(&bm[node >> 5], bit);
        if (!(old & bit)) { int p = atomicAdd(&cnt, 1); list1[p] = node; inv1[node] = p; }
    }
    __syncthreads();
    if (t == 0) { int c1 = cnt; cnts[1] = c1; cnts[0] = c1 * 16; }
}

// ---------------- gather X rows -> bf16, deriving inv0 inline (no dedup; races benign) ---------
__global__ __launch_bounds__(256)
void k_prep(const float* __restrict__ X, const int* __restrict__ senders,
            const int* __restrict__ list1, const int* __restrict__ cnts,
            int* __restrict__ inv0, ushort_t* __restrict__ Xg) {
    int r = blockIdx.x;
    int t = threadIdx.x;
    int rc = cnts[0];
    ushort_t o0 = 0, o1 = 0, o2 = 0, o3 = 0;
    if (r < rc) {
        int n = list1[r >> 4];                 // broadcast load (all lanes same addr)
        int s = senders[n * DEG + (r & 15)];
        if (t == 0) inv0[s] = r;               // duplicate writers: any winner valid (rows identical)
        float4 v = *(const float4*)(X + (size_t)s * 1024 + t * 4);
        o0 = f2bf(v.x); o1 = f2bf(v.y); o2 = f2bf(v.z); o3 = f2bf(v.w);
    }
    ushort_t* p = Xg + (size_t)r * 1024 + t * 4;
    p[0] = o0; p[1] = o1; p[2] = o2; p[3] = o3;    // pad rows -> zeros (guard-free MFMA)
}

// ---------------- bf16 MFMA logits GEMM: lgc[r] += sum_c relu(Xg[r]@W)[c]*aq[c] ----------------
// NOTE: fused relu epilogue => split-K is FORBIDDEN (relu of partial sums is wrong).
__global__ __launch_bounds__(256)
void k_logits_mfma(const ushort_t* __restrict__ Xg,  // [rows_pad][K]
                   const ushort_t* __restrict__ WT,  // [NC][K]
                   const float* __restrict__ aq, float* __restrict__ lgc,
                   const int* __restrict__ cnt, int K) {
    __shared__ short As[64 * 40];
    __shared__ short Bs[64 * 40];
    int rcnt = *cnt;
    int row0 = blockIdx.x * 64;
    if (row0 >= rcnt) return;
    int col0 = blockIdx.y * 64;
    int t = threadIdx.x;
    int w = t >> 6, lane = t & 63;

    int sr = t >> 2, sk = (t & 3) * 8;
    const ushort_t* ap = Xg + (size_t)(row0 + sr) * K + sk;
    const ushort_t* bp = WT + (size_t)(col0 + sr) * K + sk;

    int fm = lane & 15, fq = lane >> 4;
    const short* arow = As + (w * 16 + fm) * 40 + fq * 8;
    const short* brow = Bs + fm * 40 + fq * 8;

    f32x4 acc0 = {0.f,0.f,0.f,0.f}, acc1 = {0.f,0.f,0.f,0.f};
    f32x4 acc2 = {0.f,0.f,0.f,0.f}, acc3 = {0.f,0.f,0.f,0.f};

    short8 pa = *(const short8*)(ap);
    short8 pb = *(const short8*)(bp);
    for (int k0 = 0; k0 < K; k0 += 32) {
        *(short8*)(As + sr * 40 + sk) = pa;
        *(short8*)(Bs + sr * 40 + sk) = pb;
        __syncthreads();
        if (k0 + 32 < K) {
            pa = *(const short8*)(ap + k0 + 32);
            pb = *(const short8*)(bp + k0 + 32);
        }
        short8 af = *(const short8*)arow;
        short8 b0 = *(const short8*)(brow);
        short8 b1 = *(const short8*)(brow + 16 * 40);
        short8 b2 = *(const short8*)(brow + 32 * 40);
        short8 b3 = *(const short8*)(brow + 48 * 40);
        acc0 = __builtin_amdgcn_mfma_f32_16x16x32_bf16(af, b0, acc0, 0, 0, 0);
        acc1 = __builtin_amdgcn_mfma_f32_16x16x32_bf16(af, b1, acc1, 0, 0, 0);
        acc2 = __builtin_amdgcn_mfma_f32_16x16x32_bf16(af, b2, acc2, 0, 0, 0);
        acc3 = __builtin_amdgcn_mfma_f32_16x16x32_bf16(af, b3, acc3, 0, 0, 0);
        __syncthreads();
    }

    float aqv0 = aq[col0 + fm], aqv1 = aq[col0 + 16 + fm];
    float aqv2 = aq[col0 + 32 + fm], aqv3 = aq[col0 + 48 + fm];
#pragma unroll
    for (int r = 0; r < 4; r++) {
        float v = fmaxf(acc0[r], 0.f) * aqv0 + fmaxf(acc1[r], 0.f) * aqv1
                + fmaxf(acc2[r], 0.f) * aqv2 + fmaxf(acc3[r], 0.f) * aqv3;
#pragma unroll
        for (int off = 1; off < 16; off <<= 1) v += __shfl_xor(v, off);
        if (fm == 0) atomicAdd(&lgc[row0 + w * 16 + fq * 4 + r], v);
    }
}

// ---------------- generic pipelined fp32 GEMM (64x64, BK=32) -- used for mm0 only --------------
__global__ __launch_bounds__(256)
void k_matmul(const float* __restrict__ A1, const float* __restrict__ A2,
              const int* __restrict__ list, const int* __restrict__ inv,
              const float* __restrict__ B, const float* __restrict__ aq,
              float* __restrict__ C, const int* __restrict__ cnt,
              int amode, int omode, int K1, int K2, int NC, int KS) {
    __shared__ float As[32][68];
    __shared__ float Bs[32][64];
    __shared__ float rowsum[64];

    int rcnt = *cnt;
    int row0 = blockIdx.x * 64;
    if (row0 >= rcnt) return;
    int col0 = blockIdx.y * 64;
    int K = K1 + K2;
    int kbeg = blockIdx.z * KS;
    int kend = kbeg + KS; if (kend > K) kend = K;

    int t = threadIdx.x;
    int ty = t >> 4, tx = t & 15;
    int lr = t >> 2, kaoff = (t & 3) * 4;
    int grow = row0 + lr;
    bool rowValid = grow < rcnt;
    const float* rp1 = A1;
    const float* rp2 = A2;
    if (rowValid) {
        int hrow;
        if (amode == 0) hrow = grow;
        else { int node = list[grow]; hrow = (amode == 2) ? inv[node] : node; }
        rp1 = A1 + (size_t)hrow * K1;
        rp2 = A2 + (size_t)grow * K2;
    }
    const float* Bp = B + col0;
    int bidx0 = t, bidx1 = t + 256;

    auto loadA = [&](int k) -> float4 {
        if (!rowValid) return make_float4(0.f, 0.f, 0.f, 0.f);
        const float* src = (k < K1) ? (rp1 + k) : (rp2 + (k - K1));
        return *(const float4*)src;
    };
    auto loadB = [&](int idx, int k0) -> float4 {
        int row = idx >> 4, c4 = (idx & 15) * 4;
        return *(const float4*)(Bp + (size_t)(k0 + row) * NC + c4);
    };

    float4 pa0 = loadA(kbeg + kaoff);
    float4 pa1 = loadA(kbeg + kaoff + 16);
    float4 pb0 = loadB(bidx0, kbeg);
    float4 pb1 = loadB(bidx1, kbeg);

    float acc[4][4] = {};
    for (int k0 = kbeg; k0 < kend; k0 += 32) {
        As[kaoff + 0][lr] = pa0.x; As[kaoff + 1][lr] = pa0.y;
        As[kaoff + 2][lr] = pa0.z; As[kaoff + 3][lr] = pa0.w;
        As[kaoff + 16][lr] = pa1.x; As[kaoff + 17][lr] = pa1.y;
        As[kaoff + 18][lr] = pa1.z; As[kaoff + 19][lr] = pa1.w;
        *(float4*)&Bs[bidx0 >> 4][(bidx0 & 15) * 4] = pb0;
        *(float4*)&Bs[bidx1 >> 4][(bidx1 & 15) * 4] = pb1;
        __syncthreads();
        if (k0 + 32 < kend) {
            pa0 = loadA(k0 + 32 + kaoff);
            pa1 = loadA(k0 + 32 + kaoff + 16);
            pb0 = loadB(bidx0, k0 + 32);
            pb1 = loadB(bidx1, k0 + 32);
        }
#pragma unroll
        for (int kk = 0; kk < 32; kk++) {
            float4 a4 = *(const float4*)&As[kk][ty * 4];
            float4 b4 = *(const float4*)&Bs[kk][tx * 4];
            float a[4] = {a4.x, a4.y, a4.z, a4.w};
            float b[4] = {b4.x, b4.y, b4.z, b4.w};
#pragma unroll
            for (int i = 0; i < 4; i++)
#pragma unroll
                for (int j = 0; j < 4; j++) acc[i][j] += a[i] * b[j];
        }
        __syncthreads();
    }

    if (omode == 0) {
#pragma unroll
        for (int i = 0; i < 4; i++) {
            int r = row0 + ty * 4 + i;
            if (r < rcnt) {
                float* Crow = C + (size_t)r * NC + col0 + tx * 4;
#pragma unroll
                for (int j = 0; j < 4; j++) atomicAdd(&Crow[j], acc[i][j]);
            }
        }
    } else {
        if (t < 64) rowsum[t] = 0.f;
        __syncthreads();
        float aqv[4];
#pragma unroll
        for (int j = 0; j < 4; j++) aqv[j] = aq[col0 + tx * 4 + j];
#pragma unroll
        for (int i = 0; i < 4; i++) {
            float s = 0.f;
#pragma unroll
            for (int j = 0; j < 4; j++) {
                float v = acc[i][j];
                v = v > 0.f ? v : 0.f;
                s += v * aqv[j];
            }
            atomicAdd(&rowsum[ty * 4 + i], s);
        }
        __syncthreads();
        if (t < 64) {
            int r = row0 + t;
            if (r < rcnt) atomicAdd(&C[r], rowsum[t]);
        }
    }
}

// ---------------- bias + relu epilogue, dual f32 + bf16 output ----------------
__global__ void k_bias_relu(const float* __restrict__ C, const float* __restrict__ b,
                            float* __restrict__ H, ushort_t* __restrict__ Hb,
                            const int* __restrict__ cnt, int ncShift) {
    int rcnt = *cnt;
    int NC = 1 << ncShift;
    int e = blockIdx.x * 256 + threadIdx.x;
    int r = e >> ncShift;
    if (r >= rcnt) return;
    int c = e & (NC - 1);
    float v = C[(size_t)r * NC + c] + b[c];
    v = v > 0.f ? v : 0.f;
    H[(size_t)r * NC + c] = v;
    Hb[(size_t)r * NC + c] = f2bf(v);
}

// ---------------- attention aggregate (layer 0), float4-vectorized ----------------
__global__ __launch_bounds__(256)
void k_agg(const float* __restrict__ Hsrc, const int* __restrict__ invH,
           const float* __restrict__ lgc, const int* __restrict__ invL,
           const int* __restrict__ senders,
           const int* __restrict__ listN, const int* __restrict__ cntN,
           float* __restrict__ hN, int din) {
    __shared__ int   s_row[DEG];
    __shared__ float s_w[DEG];
    __shared__ float s_scale;
    int b = blockIdx.x;
    if (b >= *cntN) return;
    int n = listN[b];
    int t = threadIdx.x;
    if (t < DEG) {
        int s = senders[n * DEG + t];
        s_row[t] = invH ? invH[s] : s;
        s_w[t] = lgc[invL ? invL[s] : s];
    }
    __syncthreads();
    if (t == 0) {
        float m = -1e30f;
        for (int k = 0; k < DEG; k++) m = fmaxf(m, s_w[k]);
        float d = 0.f;
        for (int k = 0; k < DEG; k++) { float w = __expf(s_w[k] - m); s_w[k] = w; d += w; }
        s_scale = 1.f / d;
    }
    __syncthreads();
    float scale = s_scale;
    for (int dI = t * 4; dI < din; dI += 1024) {
        float4 acc = make_float4(0.f, 0.f, 0.f, 0.f);
#pragma unroll
        for (int k = 0; k < DEG; k++) {
            float w = s_w[k];
            float4 v = *(const float4*)(Hsrc + (size_t)s_row[k] * din + dI);
            acc.x += w * v.x; acc.y += w * v.y; acc.z += w * v.z; acc.w += w * v.w;
        }
        acc.x *= scale; acc.y *= scale; acc.z *= scale; acc.w *= scale;
        *(float4*)(hN + (size_t)b * din + dI) = acc;
    }
}

// ---------------- fused layer-1 tail: softmax(lgc1) agg + [h1|hN1]@lw1 + bias + relu -> h2 -----
__global__ __launch_bounds__(256)
void k_tail1(const float* __restrict__ h1, const float* __restrict__ lgc1,
             const int* __restrict__ senders, const int* __restrict__ list2,
             const int* __restrict__ inv1, const int* __restrict__ cnts,
             const float* __restrict__ lw1, const float* __restrict__ lb1,
             float* __restrict__ h2) {
    __shared__ __align__(16) float As[17][1024];  // [j][0:512)=own h1 row, [512:1024)=hN1 row
    __shared__ float sw[17][16];
    __shared__ int   srow[17][16];
    __shared__ int   orow[17];
    __shared__ float psum[8][17 * 32];
    int c2 = cnts[2];
    int t = threadIdx.x;
    int b = blockIdx.x;

    for (int i = t; i < c2 * 16; i += 256) {
        int j = i >> 4, k = i & 15;
        int s = senders[list2[j] * DEG + k];
        int rr = inv1[s];
        srow[j][k] = rr;
        sw[j][k] = lgc1[rr];
    }
    if (t < c2) orow[t] = inv1[list2[t]];
    __syncthreads();
    if (t < c2) {
        float m = -1e30f;
        for (int k = 0; k < 16; k++) m = fmaxf(m, sw[t][k]);
        float d = 0.f;
        for (int k = 0; k < 16; k++) { float w = __expf(sw[t][k] - m); sw[t][k] = w; d += w; }
        float inv = 1.f / d;
        for (int k = 0; k < 16; k++) sw[t][k] *= inv;
    }
    __syncthreads();
    // float4 staging: own row copy + weighted 16-row gather per 4-col group
    for (int e = t; e < c2 * 128; e += 256) {
        int j = e >> 7, d4 = (e & 127) * 4;
        *(float4*)&As[j][d4] = *(const float4*)&h1[(size_t)orow[j] * 512 + d4];
        float4 a = make_float4(0.f, 0.f, 0.f, 0.f);
#pragma unroll
        for (int k = 0; k < 16; k++) {
            float w = sw[j][k];
            float4 v = *(const float4*)&h1[(size_t)srow[j][k] * 512 + d4];
            a.x += w * v.x; a.y += w * v.y; a.z += w * v.z; a.w += w * v.w;
        }
        *(float4*)&As[j][512 + d4] = a;
    }
    __syncthreads();
    // GEMM: thread = (col c in 0..31, k-slice s in 0..7 of 128)
    int c = t & 31, s = t >> 5;
    int gc = b * 32 + c;
    float acc[17];
#pragma unroll
    for (int j = 0; j < 17; j++) acc[j] = 0.f;
    for (int k = s * 128; k < s * 128 + 128; k += 4) {
        float b0 = lw1[(size_t)(k + 0) * 256 + gc];
        float b1 = lw1[(size_t)(k + 1) * 256 + gc];
        float b2 = lw1[(size_t)(k + 2) * 256 + gc];
        float b3 = lw1[(size_t)(k + 3) * 256 + gc];
#pragma unroll
        for (int j = 0; j < 17; j++) {
            float4 a = *(const float4*)&As[j][k];       // LDS broadcast across the 32 c-lanes
            acc[j] += a.x * b0 + a.y * b1 + a.z * b2 + a.w * b3;
        }
    }
#pragma unroll
    for (int j = 0; j < 17; j++) psum[s][j * 32 + c] = acc[j];
    __syncthreads();
    for (int e = t; e < c2 * 32; e += 256) {
        int j = e >> 5, cc = e & 31;
        float v = 0.f;
#pragma unroll
        for (int s2 = 0; s2 < 8; s2++) v += psum[s2][j * 32 + cc];
        v += lb1[b * 32 + cc];
        h2[(size_t)j * 256 + b * 32 + cc] = v > 0.f ? v : 0.f;
    }
}

// ---------------- fused layer-2 tail: logits2 + softmax + agg + [h2|hN2]@lw2 + out matvec ------
// All GEMM phases: float4 weight loads, deep ILP, LDS partial-sum reduction (latency-bound fix).
__global__ __launch_bounds__(512)
void k_tail2(const float* __restrict__ h2, const int* __restrict__ senders,
             const int* __restrict__ inv2, const int* __restrict__ cnts,
             const float* __restrict__ aw2, const float* __restrict__ aq2,
             const float* __restrict__ lw2, const float* __restrict__ lb2,
             const float* __restrict__ ow, const float* __restrict__ ob,
             float* __restrict__ out) {
    __shared__ __align__(16) float sh2[17][256];       // 17 KB
    __shared__ __align__(16) float psum[8][17][128];   // 69.6 KB
    __shared__ __align__(16) float h3in[512];          // [h2 row14 | hN2]
    __shared__ __align__(16) float sh3[128];
    __shared__ __align__(16) float psumB[16][128];     // 8 KB
    __shared__ float slog[17];
    __shared__ float swt[16];
    __shared__ int   srow2[16];
    __shared__ int   srow14;
    int c2 = cnts[2];
    int t = threadIdx.x;
    for (int e = t; e < c2 * 64; e += 512) {
        int j = e >> 6, d4 = (e & 63) * 4;
        *(float4*)&sh2[j][d4] = *(const float4*)&h2[(size_t)j * 256 + d4];
    }
    if (t < c2) slog[t] = 0.f;
    if (t < 16) srow2[t] = inv2[senders[14 * DEG + t]];
    if (t == 31) srow14 = inv2[14];
    __syncthreads();
    // ---- logits2: dots[j][c] = sum_k sh2[j][k]*aw2[k][c]; thread=(cg 0..31, s 0..7, jg 0..1) ----
    {
        int cg = t & 31;          // cols c = cg*4 .. cg*4+3
        int s  = (t >> 5) & 7;    // k-slice [s*32, s*32+32)
        int jg = t >> 8;          // j-group: 0 -> j 0..8, 1 -> j 9..16
        int j0 = jg * 9;
        int jend = min(c2, j0 + 9);
        float4 acc[9];
#pragma unroll
        for (int i = 0; i < 9; i++) acc[i] = make_float4(0.f, 0.f, 0.f, 0.f);
        const float* ap = aw2 + cg * 4;
        for (int k = s * 32; k < s * 32 + 32; k++) {
            float4 bv = *(const float4*)(ap + (size_t)k * 128);
#pragma unroll
            for (int i = 0; i < 9; i++) {
                int j = j0 + i;
                if (j < jend) {
                    float a = sh2[j][k];
                    acc[i].x += a * bv.x; acc[i].y += a * bv.y;
                    acc[i].z += a * bv.z; acc[i].w += a * bv.w;
                }
            }
        }
#pragma unroll
        for (int i = 0; i < 9; i++) {
            int j = j0 + i;
            if (j < jend) *(float4*)&psum[s][j][cg * 4] = acc[i];
        }
    }
    __syncthreads();
    // reduce over s, relu, *aq2, accumulate logits
    for (int e = t; e < c2 * 128; e += 512) {
        int j = e >> 7, c = e & 127;
        float v = 0.f;
#pragma unroll
        for (int s = 0; s < 8; s++) v += psum[s][j][c];
        v = v > 0.f ? v : 0.f;
        atomicAdd(&slog[j], v * aq2[c]);
    }
    __syncthreads();
    if (t == 0) {
        float m = -1e30f;
        for (int k = 0; k < 16; k++) m = fmaxf(m, slog[srow2[k]]);
        float d = 0.f;
        for (int k = 0; k < 16; k++) { float w = __expf(slog[srow2[k]] - m); swt[k] = w; d += w; }
        float inv = 1.f / d;
        for (int k = 0; k < 16; k++) swt[k] *= inv;
    }
    __syncthreads();
    if (t < 256) {                       // hN2 half of h3 input
        float a = 0.f;
#pragma unroll
        for (int k = 0; k < 16; k++) a += swt[k] * sh2[srow2[k]][t];
        h3in[256 + t] = a;
    } else {                             // own-row half
        int d = t - 256;
        h3in[d] = sh2[srow14][d];
    }
    __syncthreads();
    // ---- h3 = relu(h3in @ lw2 + lb2): K=512, 128 cols; thread=(cg 0..31, s 0..15) ----
    {
        int cg = t & 31, s = t >> 5;
        float4 acc = make_float4(0.f, 0.f, 0.f, 0.f);
        const float* bp = lw2 + cg * 4;
        for (int k = s * 32; k < s * 32 + 32; k++) {
            float4 bv = *(const float4*)(bp + (size_t)k * 128);
            float a = h3in[k];
            acc.x += a * bv.x; acc.y += a * bv.y; acc.z += a * bv.z; acc.w += a * bv.w;
        }
        *(float4*)&psumB[s][cg * 4] = acc;
    }
    __syncthreads();
    if (t < 128) {
        float v = lb2[t];
#pragma unroll
        for (int s = 0; s < 16; s++) v += psumB[s][t];
        sh3[t] = v > 0.f ? v : 0.f;
    }
    __syncthreads();
    // ---- out = sh3 @ ow + ob: K=128, 128 cols; thread=(cg 0..31, s 0..15) ----
    {
        int cg = t & 31, s = t >> 5;
        float4 acc = make_float4(0.f, 0.f, 0.f, 0.f);
        const float* bp = ow + cg * 4;
        for (int k = s * 8; k < s * 8 + 8; k++) {
            float4 bv = *(const float4*)(bp + (size_t)k * 128);
            float a = sh3[k];
            acc.x += a * bv.x; acc.y += a * bv.y; acc.z += a * bv.z; acc.w += a * bv.w;
        }
        *(float4*)&psumB[s][cg * 4] = acc;
    }
    __syncthreads();
    if (t < 128) {
        float v = ob[t];
#pragma unroll
        for (int s = 0; s < 16; s++) v += psumB[s][t];
        out[t] = v;
    }
}

// ---------------- launch ----------------
extern "C" void kernel_launch(void* const* d_in, const int* in_sizes, int n_in,
                              void* d_out, int out_size, void* d_ws, size_t ws_size,
                              hipStream_t stream) {
    const float* X       = (const float*)d_in[0];
    const int*   senders = (const int*)d_in[1];
    const float* lw0 = (const float*)d_in[3];
    const float* lb0 = (const float*)d_in[4];
    const float* aw0 = (const float*)d_in[5];
    const float* aq0 = (const float*)d_in[6];
    const float* lw1 = (const float*)d_in[7];
    const float* lb1 = (const float*)d_in[8];
    const float* aw1 = (const float*)d_in[9];
    const float* aq1 = (const float*)d_in[10];
    const float* lw2 = (const float*)d_in[11];
    const float* lb2 = (const float*)d_in[12];
    const float* aw2 = (const float*)d_in[13];
    const float* aq2 = (const float*)d_in[14];
    const float* owp = (const float*)d_in[15];
    const float* obp = (const float*)d_in[16];
    float* out = (float*)d_out;

    char* ws = (char*)d_ws;
    size_t off = 0;
    auto alloc = [&](size_t nbytes) -> void* {
        void* p = ws + off;
        off += (nbytes + 255) & ~(size_t)255;
        return p;
    };
    // ---- zero-initialized region (contiguous from ws start; zeroed by k_frontier) ----
    float* lgc0     = (float*)alloc(L0PAD * 4);
    float* lgc1     = (float*)alloc(320 * 4);                 // padded to 5*64 rows
    float* C0       = (float*)alloc((size_t)MAXL1 * 512 * 4);
    ushort_t* h1b   = (ushort_t*)alloc((size_t)320 * 512 * 2); // bf16 h1, pad rows stay 0
    size_t zero_end = off;
    // ---- rest (poisoned; every read site guaranteed written first) ----
    int* inv0  = (int*)alloc(NN * 4);
    int* inv1  = (int*)alloc(NN * 4);
    int* inv2  = (int*)alloc(NN * 4);
    int* list1 = (int*)alloc(MAXL1 * 4);
    int* list2 = (int*)alloc(MAXL2 * 4);
    int* cnts  = (int*)alloc(4 * 4);
    float* dummy = (float*)alloc(16);
    ushort_t* Xg   = (ushort_t*)alloc((size_t)L0PAD * 1024 * 2);
    ushort_t* awT  = (ushort_t*)alloc((size_t)512 * 1024 * 2);   // aw0^T bf16 [512][1024]
    ushort_t* awT1 = (ushort_t*)alloc((size_t)256 * 512 * 2);    // aw1^T bf16 [256][512]
    float* hN0c = (float*)alloc((size_t)MAXL1 * 1024 * 4);
    float* h1c  = (float*)alloc((size_t)MAXL1 * 512 * 4);
    float* h2c  = (float*)alloc((size_t)MAXL2 * 256 * 4);
    (void)in_sizes; (void)n_in; (void)out_size; (void)ws_size;

    int nz4 = (int)(zero_end / 16);
    int nzb = (nz4 + 255) / 256;

    // 1. BFS levels 2+1 || zero accumulators || transpose aw0+aw1 || warm L3 with tail weights
    hipLaunchKernelGGL(k_frontier, dim3(1 + nzb + 512 + 128 + 92), dim3(256), 0, stream,
                       senders, list2, inv2, list1, inv1, cnts,
                       aw0, awT, aw1, awT1, lw1, aw2, lw2, owp, dummy,
                       (float4*)ws, nz4, nzb);
    // 2. gather X[list0] -> bf16 (list0/inv0 derived inline, no dedup)
    hipLaunchKernelGGL(k_prep, dim3(L0PAD), dim3(256), 0, stream,
                       X, senders, list1, cnts, inv0, Xg);
    // 3. layer-0 logits (bf16 MFMA, K=1024, NC=512)
    hipLaunchKernelGGL(k_logits_mfma, dim3(73, 8), dim3(256), 0, stream,
                       Xg, awT, aq0, lgc0, cnts + 0, 1024);
    // 4. layer-0 attention aggregate
    hipLaunchKernelGGL(k_agg, dim3(MAXL1), dim3(256), 0, stream,
                       X, (const int*)nullptr, lgc0, inv0, senders, list1, cnts + 1, hN0c, 1024);
    // 5. h1 = [X|hN0] @ lw0 (fp32, split-K 8)
    hipLaunchKernelGGL(k_matmul, dim3((MAXL1 + 63) / 64, 512 / 64, 8), dim3(256), 0, stream,
                       X, hN0c, list1, (int*)nullptr, lw0, aq0, C0, cnts + 1,
                       1, 0, 1024, 1024, 512, 256);
    // 6. bias+relu -> h1 (f32) + h1 (bf16)
    hipLaunchKernelGGL(k_bias_relu, dim3((MAXL1 * 512 + 255) / 256), dim3(256), 0, stream,
                       C0, lb0, h1c, h1b, cnts + 1, 9);
    // 7. layer-1 logits (bf16 MFMA, K=512, NC=256)
    hipLaunchKernelGGL(k_logits_mfma, dim3(5, 4), dim3(256), 0, stream,
                       h1b, awT1, aq1, lgc1, cnts + 1, 512);
    // 8. fused layer-1 tail -> h2 (17x256)
    hipLaunchKernelGGL(k_tail1, dim3(8), dim3(256), 0, stream,
                       h1c, lgc1, senders, list2, inv1, cnts, lw1, lb1, h2c);
    // 9. fused layer-2 tail -> out (128)
    hipLaunchKernelGGL(k_tail2, dim3(1), dim3(512), 0, stream,
                       h2c, senders, inv2, cnts, aw2, aq2, lw2, lb2, owp, obp, out);
}